// Round 10
// baseline (230.280 us; speedup 1.0000x reference)
//
#include <hip/hip_runtime.h>
#include <math.h>

#define G_MAX 384    // slot capacity (G=300 + dummies); requires G <= 383
#define O2S_MAX 512  // og sentinel 0x1FF must stay in-bounds

// 2D GT bins: 16 y-bands x 32 x-bins over [0, 900] (clamped, monotone)
#define XB 32
#define YB 16
#define NBINS 512
#define SCLX (32.0f / 900.0f)
#define SCLY (16.0f / 900.0f)

__device__ __forceinline__ int xbin(float v) {
  int b = (int)(v * SCLX);            // trunc: monotone non-decreasing
  return min(max(b, 0), XB - 1);
}
__device__ __forceinline__ int ybin(float v) {
  int b = (int)(v * SCLY);
  return min(max(b, 0), YB - 1);
}

__device__ __forceinline__ float waveSum(float v) {
#pragma unroll
  for (int o = 32; o > 0; o >>= 1) v += __shfl_down(v, o, 64);
  return v;
}

// smooth-L1 with sigma=3 (s2=9)
__device__ __forceinline__ float huber9(float x) {
  float ax = fabsf(x);
  return (ax < (1.0f / 9.0f)) ? 4.5f * x * x : ax - (0.5f / 9.0f);
}

// Exact IoU in the reference's op order. g = (x0, y0, x1+1, y1+1)
__device__ __forceinline__ float iouExact(float bx0, float by0, float bx1, float by1,
                                          float areab, float4 g, float areag) {
  float gx1 = g.z - 1.0f, gy1 = g.w - 1.0f;  // exact inverse of staged +1 (coords < 2^24)
  float iw = fminf(bx1, gx1) - fmaxf(bx0, g.x) + 1.0f;
  float ih = fminf(by1, gy1) - fmaxf(by0, g.y) + 1.0f;
  float inter = fmaxf(iw, 0.f) * fmaxf(ih, 0.f);
  float uni = areab + areag - inter;
  return inter / fmaxf(uni, 1.0f);
}

// Inverse comparison key: key = (areaB+areaG)*rcp(inter); argmax iou == argmin
// key (uint compare on positive floats). ONE-CLAMP trick: inter = max(iw,0)*ih.
//   ih >= 0: identical to the two-clamp value (positive-overlap keys exact).
//   ih <  0: key negative/-inf -> uint >= 0x80000000 -> loses under min-tracking.
//   iw <= 0, ih > 0: inter = +0 -> key = +inf -> loses to all finite positives.
// Zero-overlap/invalid internal order is output-invariant (winners recomputed
// exactly with validity masks -> label 0 / fg=false / value 0). 2D-band
// pruning only removes members of this class (pruned GT fails x- or
// y-overlap by the monotone-bin argument) -> output unchanged.
// Low 9 bits carry ORIGINAL g: min-ties resolve to smallest g (jax stable).
__device__ __forceinline__ uint32_t packKey(float x0, float y0, float x1p, float y1p,
                                            float area, float4 gb, float ga,
                                            uint32_t g) {
  float iw = fminf(x1p, gb.z) - fmaxf(x0, gb.x);
  float ih = fminf(y1p, gb.w) - fmaxf(y0, gb.y);
  float inter = fmaxf(iw, 0.f) * ih;
  float key = (area + ga) * __builtin_amdgcn_rcpf(inter);
  return (__float_as_uint(key) & 0xFFFFFE00u) | g;
}

__global__ __launch_bounds__(256) void retina_main(
    const float* __restrict__ pred_cls,   // (n, A, 2)
    const float* __restrict__ rpn_num,    // (n, A, 2)
    const float* __restrict__ pred_reg,   // (n, A, 8)
    const float* __restrict__ anchors,    // (A, 4)
    const float* __restrict__ rpn_iou,    // (n, A, 2)
    const float* __restrict__ boxes,      // (n, G, 5)
    int A, int G, int totalBlocks, int nB,
    double* __restrict__ partial,         // (nB, 8) doubles, private per block
    unsigned int* __restrict__ cnt,       // ticket (memset to 0 per launch)
    float* __restrict__ out)              // 4 floats
{
  __shared__ float4 sBox[G_MAX];          // (yband,xbin)-ordered: x0,y0,x1+1,y1+1
  __shared__ float2 sMeta[G_MAX];         // (area | 1e30 invalid, orig-g bits)
  __shared__ unsigned short sO2S[O2S_MAX];// orig g (incl. 0x1FF sentinel) -> slot
  __shared__ int sCnt[NBINS];             // hist, then scatter cursors
  __shared__ int sStart[NBINS + 1];       // exclusive prefix (window table)
  __shared__ int sWsum[4];
  __shared__ float sWaveMax[4][2];
  __shared__ float sSpanX, sSpanY;
  __shared__ float sRed[4][7];
  __shared__ double sRedD[4][7];
  __shared__ float sStash[128][10];       // decoded boxes of needy anchors
  __shared__ float2 sRes[128];            // aval/bval results (by duo id)
  __shared__ unsigned char sList[128];    // slot -> duo id
  __shared__ int sNum;
  __shared__ int sLast;

  const int img = blockIdx.y;
  const int seg = threadIdx.x & 1;        // SPLIT=2 lanes per anchor
  const int duo = threadIdx.x >> 1;       // duo id 0..127, one anchor each
  const int i   = blockIdx.x * 128 + duo;
  const int ic  = (i < A) ? i : (A - 1);
  const float* gtb = boxes + (size_t)img * G * 5;

  // ---- hoisted per-anchor loads: HBM latency hides under the GT prep below --
  float4 a4 = *(const float4*)(anchors + (size_t)ic * 4);
  float ax0 = a4.x, ay0 = a4.y, ax1 = a4.z, ay1 = a4.w;
  float aw = ax1 - ax0 + 1.0f, ah = ay1 - ay0 + 1.0f;
  float areaa = aw * ah;
  float acx = ax0 + 0.5f * aw, acy = ay0 + 0.5f * ah;
  float ax1p = ax1 + 1.0f, ay1p = ay1 + 1.0f;

  float d0 = 0.f, d1 = 0.f, d2 = 0.f, d3 = 0.f;
  float d4 = 0.f, d5 = 0.f, d6 = 0.f, d7 = 0.f;
  float pcv0 = 0.f, pcv1 = 0.f, riv0 = 0.f, riv1 = 0.f, sn0 = 0.f, sn1 = 0.f;
  if (seg == 0) {
    const float* dp = pred_reg + ((size_t)img * A + ic) * 8;
    d0 = dp[0]; d1 = dp[1]; d2 = dp[2]; d3 = dp[3];
    d4 = dp[4]; d5 = dp[5]; d6 = dp[6]; d7 = dp[7];
    const float* pc = pred_cls + ((size_t)img * A + ic) * 2;
    pcv0 = pc[0]; pcv1 = pc[1];
    const float* ri = rpn_iou + ((size_t)img * A + ic) * 2;
    riv0 = ri[0]; riv1 = ri[1];
    const float* sp = rpn_num + ((size_t)img * A + ic) * 2;
    sn0 = sp[0]; sn1 = sp[1];
  }

  // ---- in-block GT prep: counting sort by (yband, xbin) ----
  if (threadIdx.x == 0) sNum = 0;
  for (int b = threadIdx.x; b < NBINS; b += 256) sCnt[b] = 0;
  // dummy slots [G, G_MAX) + sentinel map entries [G, O2S_MAX) -> dummy slot G
  for (int s = G + threadIdx.x; s < G_MAX; s += 256) {
    sBox[s] = make_float4(0.f, 0.f, 1.f, 1.f);
    sMeta[s] = make_float2(1e30f, __uint_as_float((unsigned)s));
  }
  for (int s = G + threadIdx.x; s < O2S_MAX; s += 256)
    sO2S[s] = (unsigned short)G;
  __syncthreads();

  // one global pass: cache rows in registers (G<=512 -> <=2 rows per thread)
  float rx0[2], ry0[2], rx1[2], ry1[2], rlb[2];
  int ng = 0;
  for (int g = threadIdx.x; g < G; g += 256, ++ng) {
    rx0[ng] = gtb[g * 5 + 0]; ry0[ng] = gtb[g * 5 + 1];
    rx1[ng] = gtb[g * 5 + 2]; ry1[ng] = gtb[g * 5 + 3];
    rlb[ng] = gtb[g * 5 + 4];
    atomicAdd(&sCnt[(ybin(ry0[ng]) << 5) | xbin(rx0[ng])], 1);
  }
  __syncthreads();

  // wave-scan exclusive prefix over 512 bins (2 bins/thread)
  {
    int t = threadIdx.x;
    int b0 = sCnt[t * 2 + 0], b1 = sCnt[t * 2 + 1];
    int tsum = b0 + b1;
    int lane = t & 63, wid = t >> 6;
    int incl = tsum;
#pragma unroll
    for (int o = 1; o < 64; o <<= 1) {
      int u = __shfl_up(incl, o, 64);
      if (lane >= o) incl += u;
    }
    if (lane == 63) sWsum[wid] = incl;
    __syncthreads();
    int woff = 0;
    for (int w = 0; w < wid; ++w) woff += sWsum[w];   // uniform per wave
    int excl = woff + incl - tsum;
    sStart[t * 2 + 0] = excl;
    sStart[t * 2 + 1] = excl + b0;
    if (t == 255) sStart[NBINS] = excl + tsum;        // == G
    sCnt[t * 2 + 0] = excl;
    sCnt[t * 2 + 1] = excl + b0;
  }
  __syncthreads();

  // scatter (within-bin order arbitrary: harmless, keys carry orig g)
  float mspanX = 0.f, mspanY = 0.f;
  {
    int g = threadIdx.x;
    for (int k = 0; k < ng; ++k, g += 256) {
      float x0 = rx0[k], y0 = ry0[k], x1 = rx1[k], y1 = ry1[k], lb = rlb[k];
      int pos = atomicAdd(&sCnt[(ybin(y0) << 5) | xbin(x0)], 1);
      float x1p = x1 + 1.0f, y1p = y1 + 1.0f;
      sBox[pos] = make_float4(x0, y0, x1p, y1p);
      sMeta[pos] = make_float2(
          (lb != -1.0f) ? (x1 - x0 + 1.0f) * (y1 - y0 + 1.0f) : 1e30f,
          __uint_as_float((unsigned)g));
      sO2S[g] = (unsigned short)pos;
      mspanX = fmaxf(mspanX, x1p - x0);
      mspanY = fmaxf(mspanY, y1p - y0);
    }
  }
#pragma unroll
  for (int m = 32; m > 0; m >>= 1) {
    mspanX = fmaxf(mspanX, __shfl_xor(mspanX, m, 64));
    mspanY = fmaxf(mspanY, __shfl_xor(mspanY, m, 64));
  }
  {
    int lane = threadIdx.x & 63, wid = threadIdx.x >> 6;
    if (lane == 0) { sWaveMax[wid][0] = mspanX; sWaveMax[wid][1] = mspanY; }
  }
  __syncthreads();
  if (threadIdx.x == 0) {
    sSpanX = fmaxf(fmaxf(sWaveMax[0][0], sWaveMax[1][0]),
                   fmaxf(sWaveMax[2][0], sWaveMax[3][0])) + 1.0f;  // +1 px slack
    sSpanY = fmaxf(fmaxf(sWaveMax[0][1], sWaveMax[1][1]),
                   fmaxf(sWaveMax[2][1], sWaveMax[3][1])) + 1.0f;
  }
  __syncthreads();
  const float spanX = sSpanX, spanY = sSpanY;

  float t_cls = 0.f, t_bbox = 0.f, t_iou = 0.f, t_num = 0.f;
  float t_npos = 0.f, t_nfg = 0.f, t_ncnt = 0.f;

  const float BBOX_CLIP = 4.1351666f;  // log(1000/16)

  // ---------------- phase 1: anchor-vs-gt top-2, 2D-banded window ----------
  // Superset proof: any GT with x- AND y-overlap has gx0 in [ax0-spanX, ax1p],
  // gy0 in [ay0-spanY, ay1p] -> its (ybin,xbin) lies in the iterated rectangle
  // (monotone clamped bins, same formula at build and query).
  uint32_t an1 = 0xFFFFFFFFu, an2 = 0xFFFFFFFFu;
  {
    int xb0 = xbin(ax0 - spanX);
    int xb1 = xbin(ax1p);
    int yb0 = ybin(ay0 - spanY);
    int yb1 = ybin(ay1p);
    for (int yb = yb0; yb <= yb1; ++yb) {
      int lo = sStart[(yb << 5) + xb0];
      int hi = sStart[(yb << 5) + xb1 + 1];
#pragma unroll 2
      for (int s = lo + seg; s < hi; s += 2) {
        float4 gb = sBox[s];
        float2 mt = sMeta[s];
        uint32_t pk = packKey(ax0, ay0, ax1p, ay1p, areaa, gb, mt.x,
                              __float_as_uint(mt.y));
        uint32_t h = max(pk, an1);
        an1 = min(an1, pk);
        an2 = min(an2, h);
      }
    }
  }

  // merge the duo's 2 lanes
  {
    uint32_t o1 = (uint32_t)__shfl_xor((int)an1, 1, 64);
    uint32_t o2 = (uint32_t)__shfl_xor((int)an2, 1, 64);
    uint32_t hi = max(an1, o1);
    an1 = min(an1, o1);
    an2 = min(min(an2, o2), hi);
  }

  bool fg0 = false, fg1 = false, needy = false;

  if (seg == 0 && i < A) {
    // winning ORIGINAL indices -> slots (sentinel 0x1FF -> dummy slot G)
    int og0 = (int)(an1 & 0x1FFu);
    int og1 = (int)(an2 & 0x1FFu);
    int s0 = sO2S[og0];
    int s1 = sO2S[og1];

    // exact recompute of winning values (reference op order, explicit validity)
    float4 g0 = sBox[s0]; float a0 = sMeta[s0].x; bool val0 = a0 < 1e29f;
    float v0 = val0 ? iouExact(ax0, ay0, ax1, ay1, areaa, g0, a0) : -1.0f;
    float4 g1 = sBox[s1]; float a1 = sMeta[s1].x; bool val1 = a1 < 1e29f;
    float v1 = val1 ? iouExact(ax0, ay0, ax1, ay1, areaa, g1, a1) : -1.0f;

    // labels: >=0.5 -> 1, <0.4 -> 0, else -1
    float la  = (v0 >= 0.5f) ? 1.0f : ((v0 < 0.4f) ? 0.0f : -1.0f);
    float lbv = (v1 >= 0.5f) ? 1.0f : ((v1 < 0.4f) ? 0.0f : -1.0f);
    float lab0 = la;
    float lab1 = lbv - (((la == 0.0f) && (lbv != 0.0f)) ? 1.0f : 0.0f);

    // ---- focal classification loss ----
    {
      float pv = pcv0;
      if (lab0 != -1.0f) {
        float l = (lab0 == 1.0f)
                      ? 0.25f * (1.0f - pv) * (1.0f - pv) * logf(pv)
                      : 0.75f * pv * pv * logf(1.0f - pv);
        t_cls -= l;
      }
      if (lab0 > 0.f) t_npos += 1.f;
      float qv = pcv1;
      if (lab1 != -1.0f) {
        float l = (lab1 == 1.0f)
                      ? 0.25f * (1.0f - qv) * (1.0f - qv) * logf(qv)
                      : 0.75f * qv * qv * logf(1.0f - qv);
        t_cls -= l;
      }
      if (lab1 > 0.f) t_npos += 1.f;
    }

    fg0 = (lab0 != 0.0f) && (lab0 != -1.0f);
    fg1 = (lab1 != 0.0f) && (lab1 != -1.0f);

    // fast reciprocals for the bbox-target divides (rel err ~1e-7, harmless)
    float raw = __builtin_amdgcn_rcpf(aw), rah = __builtin_amdgcn_rcpf(ah);

    // ---- bbox smooth-L1 vs bbox_transform(anchor, matched gt) ----
    if (fg0) {
      float mx1 = g0.z - 1.0f, my1 = g0.w - 1.0f;
      float gw = mx1 - g0.x + 1.0f, gh = my1 - g0.y + 1.0f;
      float gcx = g0.x + 0.5f * gw, gcy = g0.y + 0.5f * gh;
      float t0 = (gcx - acx) * raw, t1v = (gcy - acy) * rah;
      float t2 = logf(gw * raw), t3 = logf(gh * rah);
      t_bbox += huber9(d0 - t0) + huber9(d1 - t1v) + huber9(d2 - t2) + huber9(d3 - t3);
      t_nfg += 1.f;
    }
    if (fg1) {
      float mx1 = g1.z - 1.0f, my1 = g1.w - 1.0f;
      float gw = mx1 - g1.x + 1.0f, gh = my1 - g1.y + 1.0f;
      float gcx = g1.x + 0.5f * gw, gcy = g1.y + 0.5f * gh;
      float t0 = (gcx - acx) * raw, t1v = (gcy - acy) * rah;
      float t2 = logf(gw * raw), t3 = logf(gh * rah);
      t_bbox += huber9(d4 - t0) + huber9(d5 - t1v) + huber9(d6 - t2) + huber9(d7 - t3);
      t_nfg += 1.f;
    }

    // ---- num softmax loss ----
    {
      int nl = ((lab0 > 0.f) ? 1 : 0) + ((lab1 > 0.f) ? 1 : 0) - 1;
      if (nl != -1) {
        float m = fmaxf(sn0, sn1);
        float lse = m + logf(expf(sn0 - m) + expf(sn1 - m));
        float picked = ((nl == 0) ? sn0 : sn1) - lse;
        t_num -= picked;
        t_ncnt += 1.f;
      }
    }

    // ---- enqueue for phase 2 (decoded-box argmaxes) only if fg ----
    needy = fg0 || fg1;
    if (needy) {
      // decode predicted boxes (identical expressions to the original)
      float p0cx = acx + d0 * aw, p0cy = acy + d1 * ah;
      float p0w = aw * expf(fminf(d2, BBOX_CLIP));
      float p0h = ah * expf(fminf(d3, BBOX_CLIP));
      float b0x0 = p0cx - 0.5f * p0w, b0y0 = p0cy - 0.5f * p0h;
      float b0x1 = p0cx + 0.5f * p0w, b0y1 = p0cy + 0.5f * p0h;
      float area0 = (b0x1 - b0x0 + 1.0f) * (b0y1 - b0y0 + 1.0f);

      float p1cx = acx + d4 * aw, p1cy = acy + d5 * ah;
      float p1w = aw * expf(fminf(d6, BBOX_CLIP));
      float p1h = ah * expf(fminf(d7, BBOX_CLIP));
      float b1x0 = p1cx - 0.5f * p1w, b1y0 = p1cy - 0.5f * p1h;
      float b1x1 = p1cx + 0.5f * p1w, b1y1 = p1cy + 0.5f * p1h;
      float area1 = (b1x1 - b1x0 + 1.0f) * (b1y1 - b1y0 + 1.0f);

      int slot = atomicAdd(&sNum, 1);
      sList[slot] = (unsigned char)duo;
      float* st = sStash[slot];
      st[0] = b0x0; st[1] = b0y0; st[2] = b0x1; st[3] = b0y1; st[4] = area0;
      st[5] = b1x0; st[6] = b1y0; st[7] = b1x1; st[8] = b1y1; st[9] = area1;
    }
  }
  __syncthreads();

  // -------- phase 2: compacted decoded-box argmaxes (2D-banded windows) ------
  {
    int num = sNum;
    for (int sb = 0; sb < num; sb += 64) {
      int slot = sb + (threadIdx.x >> 2);
      int wseg = threadIdx.x & 3;
      if (slot < num) {   // uniform across each quad -> shfl butterfly safe
        const float* st = sStash[slot];
        float c0x0 = st[0], c0y0 = st[1], c0x1 = st[2], c0y1 = st[3], car0 = st[4];
        float c1x0 = st[5], c1y0 = st[6], c1x1 = st[7], c1y1 = st[8], car1 = st[9];
        float c0x1p = c0x1 + 1.0f, c0y1p = c0y1 + 1.0f;
        float c1x1p = c1x1 + 1.0f, c1y1p = c1y1 + 1.0f;

        uint32_t am = 0xFFFFFFFFu;                     // box 0 best
        uint32_t bk1 = 0xFFFFFFFFu, bk2 = 0xFFFFFFFFu; // box 1 best/2nd

        // union 2D window of both decoded boxes (clamped bins handle wild
        // extents; extra GTs are zero-overlap -> invariant)
        int xb0 = xbin(fminf(c0x0, c1x0) - spanX);
        int xb1 = xbin(fmaxf(c0x1p, c1x1p));
        int yb0 = ybin(fminf(c0y0, c1y0) - spanY);
        int yb1 = ybin(fmaxf(c0y1p, c1y1p));
        for (int yb = yb0; yb <= yb1; ++yb) {
          int lo = sStart[(yb << 5) + xb0];
          int hi = sStart[(yb << 5) + xb1 + 1];
#pragma unroll 2
          for (int s = lo + wseg; s < hi; s += 4) {
            float4 gb = sBox[s];
            float2 mt = sMeta[s];
            uint32_t og = __float_as_uint(mt.y);
            am = min(am, packKey(c0x0, c0y0, c0x1p, c0y1p, car0, gb, mt.x, og));
            uint32_t pk = packKey(c1x0, c1y0, c1x1p, c1y1p, car1, gb, mt.x, og);
            uint32_t hib = max(pk, bk1);
            bk1 = min(bk1, pk);
            bk2 = min(bk2, hib);
          }
        }

#pragma unroll
        for (int m = 1; m <= 2; m <<= 1) {
          am = min(am, (uint32_t)__shfl_xor((int)am, m, 64));
          uint32_t q1 = (uint32_t)__shfl_xor((int)bk1, m, 64);
          uint32_t q2 = (uint32_t)__shfl_xor((int)bk2, m, 64);
          uint32_t hib = max(bk1, q1);
          bk1 = min(bk1, q1);
          bk2 = min(min(bk2, q2), hib);
        }

        if (wseg == 0) {
          int ai  = (int)(am  & 0x1FFu);  // ORIGINAL indices (reference semantics)
          int bi  = (int)(bk1 & 0x1FFu);
          int bi2 = (int)(bk2 & 0x1FFu);
          int sa = sO2S[ai];
          float4 ga4 = sBox[sa]; float aav = sMeta[sa].x;
          float aval = (aav < 1e29f) ? iouExact(c0x0, c0y0, c0x1, c0y1, car0, ga4, aav) : 0.0f;
          int bIdx = (ai == bi) ? bi2 : bi;  // b with b[ai] zeroed, then argmax
          int sb2 = sO2S[bIdx];
          float4 gb4 = sBox[sb2]; float abv = sMeta[sb2].x;
          float bval = (abv < 1e29f) ? iouExact(c1x0, c1y0, c1x1, c1y1, car1, gb4, abv) : 0.0f;
          sRes[sList[slot]] = make_float2(aval, bval);
        }
      }
    }
  }
  __syncthreads();

  // ---- IoU L1 loss (owner lane reads phase-2 result) ----
  if (needy) {   // implies seg==0 && i<A
    float2 r = sRes[duo];
    if (fg0) t_iou += fabsf(riv0 - r.x);
    if (fg1) t_iou += fabsf(riv1 - fmaxf(r.y, 0.0f));
  }

  // block reduction: wave shuffle -> LDS -> one private record per block.
  float vals[7] = {t_cls, t_bbox, t_iou, t_num, t_npos, t_nfg, t_ncnt};
  int lane = threadIdx.x & 63;
  int wid = threadIdx.x >> 6;
#pragma unroll
  for (int k = 0; k < 7; ++k) {
    float s = waveSum(vals[k]);
    if (lane == 0) sRed[wid][k] = s;
  }
  __syncthreads();
  size_t bid = (size_t)blockIdx.y * gridDim.x + blockIdx.x;
  if (threadIdx.x < 7) {
    double s = (double)sRed[0][threadIdx.x] + (double)sRed[1][threadIdx.x] +
               (double)sRed[2][threadIdx.x] + (double)sRed[3][threadIdx.x];
    partial[bid * 8 + threadIdx.x] = s;    // 64-B record, no contention
  }
  // ticket: ONE same-line atomic per block (r1's 8/block serialized at 114 us;
  // 1/block is ~7 us spread across the kernel -> hidden under compute)
  __threadfence();                         // release partial record device-wide
  __syncthreads();
  if (threadIdx.x == 0) {
    unsigned int old = atomicAdd(cnt, 1u);
    sLast = (old == (unsigned int)(totalBlocks - 1)) ? 1 : 0;
  }
  __syncthreads();

  // last block reduces all partials (atomic reads: plain loads are NOT safe
  // across per-XCD L2s) and writes the 4 outputs -> no finalize dispatch.
  if (sLast) {
    __threadfence();
    double loc[7] = {0.0, 0.0, 0.0, 0.0, 0.0, 0.0, 0.0};
    for (int b = threadIdx.x; b < nB; b += 256) {
      double* r = partial + (size_t)b * 8;
#pragma unroll
      for (int k = 0; k < 7; ++k) loc[k] += atomicAdd(&r[k], 0.0);
    }
#pragma unroll
    for (int k = 0; k < 7; ++k) {
      double v = loc[k];
#pragma unroll
      for (int o = 32; o > 0; o >>= 1) v += __shfl_down(v, o, 64);
      if (lane == 0) sRedD[wid][k] = v;
    }
    __syncthreads();
    if (threadIdx.x == 0) {
      double t[7];
#pragma unroll
      for (int k = 0; k < 7; ++k)
        t[k] = sRedD[0][k] + sRedD[1][k] + sRedD[2][k] + sRedD[3][k];
      double dpos = t[4] > 1.0 ? t[4] : 1.0;
      double dfg  = t[5] > 1.0 ? t[5] : 1.0;
      double dcnt = t[6] > 1.0 ? t[6] : 1.0;
      out[0] = (float)(t[0] / dpos);
      out[1] = (float)(2.0 * t[1] / dfg);
      out[2] = (float)(2.0 * t[2] / dfg);
      out[3] = (float)(t[3] / dcnt);
    }
  }
}

extern "C" void kernel_launch(void* const* d_in, const int* in_sizes, int n_in,
                              void* d_out, int out_size, void* d_ws, size_t ws_size,
                              hipStream_t stream) {
  const float* pred_cls = (const float*)d_in[0];
  const float* rpn_num  = (const float*)d_in[1];
  const float* pred_reg = (const float*)d_in[2];
  const float* anchors  = (const float*)d_in[3];
  const float* rpn_iou  = (const float*)d_in[4];
  const float* boxes    = (const float*)d_in[5];
  // d_in[6] = im_info: unused by the reference math

  int A = in_sizes[3] / 4;
  int n = in_sizes[0] / (2 * A);
  int G = in_sizes[5] / (5 * n);

  int nBx = (A + 127) / 128;  // 128 anchors per block (SPLIT=2)
  int nB = nBx * n;

  double* partial = (double*)d_ws;                 // (nB, 8) doubles
  unsigned int* cnt = (unsigned int*)((char*)d_ws + (size_t)nB * 8 * sizeof(double));

  hipMemsetAsync(cnt, 0, sizeof(unsigned int), stream);  // ticket reset (graph-safe)

  dim3 grid(nBx, n, 1);
  // ONE kernel dispatch (+1 memset): wall model ~60 us fixed + main + ~6 us/gap
  retina_main<<<grid, dim3(256, 1, 1), 0, stream>>>(
      pred_cls, rpn_num, pred_reg, anchors, rpn_iou, boxes,
      A, G, nB, nB, partial, cnt, (float*)d_out);
}

// Round 11
// 128.391 us; speedup vs baseline: 1.7936x; 1.7936x over previous
//
#include <hip/hip_runtime.h>
#include <math.h>

#define G_MAX 384    // slot capacity (G=300 + dummies); requires G <= 383
#define O2S_MAX 512  // og sentinel 0x1FF must stay in-bounds

// 2D GT bins: 16 y-bands x 32 x-bins over [0, 900] (clamped, monotone)
#define XB 32
#define YB 16
#define NBINS 512
#define SCLX (32.0f / 900.0f)
#define SCLY (16.0f / 900.0f)

__device__ __forceinline__ int xbin(float v) {
  int b = (int)(v * SCLX);            // trunc: monotone non-decreasing
  return min(max(b, 0), XB - 1);
}
__device__ __forceinline__ int ybin(float v) {
  int b = (int)(v * SCLY);
  return min(max(b, 0), YB - 1);
}

__device__ __forceinline__ float waveSum(float v) {
#pragma unroll
  for (int o = 32; o > 0; o >>= 1) v += __shfl_down(v, o, 64);
  return v;
}

// smooth-L1 with sigma=3 (s2=9)
__device__ __forceinline__ float huber9(float x) {
  float ax = fabsf(x);
  return (ax < (1.0f / 9.0f)) ? 4.5f * x * x : ax - (0.5f / 9.0f);
}

// Exact IoU in the reference's op order. g = (x0, y0, x1+1, y1+1)
__device__ __forceinline__ float iouExact(float bx0, float by0, float bx1, float by1,
                                          float areab, float4 g, float areag) {
  float gx1 = g.z - 1.0f, gy1 = g.w - 1.0f;  // exact inverse of staged +1 (coords < 2^24)
  float iw = fminf(bx1, gx1) - fmaxf(bx0, g.x) + 1.0f;
  float ih = fminf(by1, gy1) - fmaxf(by0, g.y) + 1.0f;
  float inter = fmaxf(iw, 0.f) * fmaxf(ih, 0.f);
  float uni = areab + areag - inter;
  return inter / fmaxf(uni, 1.0f);
}

// Inverse comparison key: key = (areaB+areaG)*rcp(inter); argmax iou == argmin
// key (uint compare on positive floats). ONE-CLAMP trick: inter = max(iw,0)*ih.
//   ih >= 0: identical to the two-clamp value (positive-overlap keys exact).
//   ih <  0: key negative/-inf -> uint >= 0x80000000 -> loses under min-tracking.
//   iw <= 0, ih > 0: inter = +0 -> key = +inf -> loses to all finite positives.
// Zero-overlap/invalid internal order is output-invariant (winners recomputed
// exactly with validity masks -> label 0 / fg=false / value 0). 2D-band
// pruning only removes members of this class (pruned GT fails x- or
// y-overlap by the monotone-bin argument) -> output unchanged.
// Low 9 bits carry ORIGINAL g: min-ties resolve to smallest g (jax stable).
__device__ __forceinline__ uint32_t packKey(float x0, float y0, float x1p, float y1p,
                                            float area, float4 gb, float ga,
                                            uint32_t g) {
  float iw = fminf(x1p, gb.z) - fmaxf(x0, gb.x);
  float ih = fminf(y1p, gb.w) - fmaxf(y0, gb.y);
  float inter = fmaxf(iw, 0.f) * ih;
  float key = (area + ga) * __builtin_amdgcn_rcpf(inter);
  return (__float_as_uint(key) & 0xFFFFFE00u) | g;
}

__global__ __launch_bounds__(256) void retina_main(
    const float* __restrict__ pred_cls,   // (n, A, 2)
    const float* __restrict__ rpn_num,    // (n, A, 2)
    const float* __restrict__ pred_reg,   // (n, A, 8)
    const float* __restrict__ anchors,    // (A, 4)
    const float* __restrict__ rpn_iou,    // (n, A, 2)
    const float* __restrict__ boxes,      // (n, G, 5)
    int A, int G,
    double* __restrict__ partial)         // (nB, 8) doubles, private per block
{
  __shared__ float4 sBox[G_MAX];          // (yband,xbin)-ordered: x0,y0,x1+1,y1+1
  __shared__ float2 sMeta[G_MAX];         // (area | 1e30 invalid, orig-g bits)
  __shared__ unsigned short sO2S[O2S_MAX];// orig g (incl. 0x1FF sentinel) -> slot
  __shared__ int sCnt[NBINS];             // hist, then scatter cursors
  __shared__ int sStart[NBINS + 1];       // exclusive prefix (window table)
  __shared__ int sWsum[4];
  __shared__ float sWaveMax[4][2];
  __shared__ float sSpanX, sSpanY;
  __shared__ float sRed[4][7];
  __shared__ float sStash[128][10];       // decoded boxes of needy anchors
  __shared__ float2 sRes[128];            // aval/bval results (by duo id)
  __shared__ unsigned char sList[128];    // slot -> duo id
  __shared__ int sNum;

  const int img = blockIdx.y;
  const int seg = threadIdx.x & 1;        // SPLIT=2 lanes per anchor
  const int duo = threadIdx.x >> 1;       // duo id 0..127, one anchor each
  const int i   = blockIdx.x * 128 + duo;
  const int ic  = (i < A) ? i : (A - 1);
  const float* gtb = boxes + (size_t)img * G * 5;

  // ---- hoisted per-anchor loads: HBM latency hides under the GT prep below --
  float4 a4 = *(const float4*)(anchors + (size_t)ic * 4);
  float ax0 = a4.x, ay0 = a4.y, ax1 = a4.z, ay1 = a4.w;
  float aw = ax1 - ax0 + 1.0f, ah = ay1 - ay0 + 1.0f;
  float areaa = aw * ah;
  float acx = ax0 + 0.5f * aw, acy = ay0 + 0.5f * ah;
  float ax1p = ax1 + 1.0f, ay1p = ay1 + 1.0f;

  float d0 = 0.f, d1 = 0.f, d2 = 0.f, d3 = 0.f;
  float d4 = 0.f, d5 = 0.f, d6 = 0.f, d7 = 0.f;
  float pcv0 = 0.f, pcv1 = 0.f, riv0 = 0.f, riv1 = 0.f, sn0 = 0.f, sn1 = 0.f;
  if (seg == 0) {
    const float* dp = pred_reg + ((size_t)img * A + ic) * 8;
    d0 = dp[0]; d1 = dp[1]; d2 = dp[2]; d3 = dp[3];
    d4 = dp[4]; d5 = dp[5]; d6 = dp[6]; d7 = dp[7];
    const float* pc = pred_cls + ((size_t)img * A + ic) * 2;
    pcv0 = pc[0]; pcv1 = pc[1];
    const float* ri = rpn_iou + ((size_t)img * A + ic) * 2;
    riv0 = ri[0]; riv1 = ri[1];
    const float* sp = rpn_num + ((size_t)img * A + ic) * 2;
    sn0 = sp[0]; sn1 = sp[1];
  }

  // ---- in-block GT prep: counting sort by (yband, xbin) ----
  if (threadIdx.x == 0) sNum = 0;
  for (int b = threadIdx.x; b < NBINS; b += 256) sCnt[b] = 0;
  // dummy slots [G, G_MAX) + sentinel map entries [G, O2S_MAX) -> dummy slot G
  for (int s = G + threadIdx.x; s < G_MAX; s += 256) {
    sBox[s] = make_float4(0.f, 0.f, 1.f, 1.f);
    sMeta[s] = make_float2(1e30f, __uint_as_float((unsigned)s));
  }
  for (int s = G + threadIdx.x; s < O2S_MAX; s += 256)
    sO2S[s] = (unsigned short)G;
  __syncthreads();

  // one global pass: cache rows in registers (G<=512 -> <=2 rows per thread)
  float rx0[2], ry0[2], rx1[2], ry1[2], rlb[2];
  int ng = 0;
  for (int g = threadIdx.x; g < G; g += 256, ++ng) {
    rx0[ng] = gtb[g * 5 + 0]; ry0[ng] = gtb[g * 5 + 1];
    rx1[ng] = gtb[g * 5 + 2]; ry1[ng] = gtb[g * 5 + 3];
    rlb[ng] = gtb[g * 5 + 4];
    atomicAdd(&sCnt[(ybin(ry0[ng]) << 5) | xbin(rx0[ng])], 1);
  }
  __syncthreads();

  // wave-scan exclusive prefix over 512 bins (2 bins/thread)
  {
    int t = threadIdx.x;
    int b0 = sCnt[t * 2 + 0], b1 = sCnt[t * 2 + 1];
    int tsum = b0 + b1;
    int lane = t & 63, wid = t >> 6;
    int incl = tsum;
#pragma unroll
    for (int o = 1; o < 64; o <<= 1) {
      int u = __shfl_up(incl, o, 64);
      if (lane >= o) incl += u;
    }
    if (lane == 63) sWsum[wid] = incl;
    __syncthreads();
    int woff = 0;
    for (int w = 0; w < wid; ++w) woff += sWsum[w];   // uniform per wave
    int excl = woff + incl - tsum;
    sStart[t * 2 + 0] = excl;
    sStart[t * 2 + 1] = excl + b0;
    if (t == 255) sStart[NBINS] = excl + tsum;        // == G
    sCnt[t * 2 + 0] = excl;
    sCnt[t * 2 + 1] = excl + b0;
  }
  __syncthreads();

  // scatter (within-bin order arbitrary: harmless, keys carry orig g)
  float mspanX = 0.f, mspanY = 0.f;
  {
    int g = threadIdx.x;
    for (int k = 0; k < ng; ++k, g += 256) {
      float x0 = rx0[k], y0 = ry0[k], x1 = rx1[k], y1 = ry1[k], lb = rlb[k];
      int pos = atomicAdd(&sCnt[(ybin(y0) << 5) | xbin(x0)], 1);
      float x1p = x1 + 1.0f, y1p = y1 + 1.0f;
      sBox[pos] = make_float4(x0, y0, x1p, y1p);
      sMeta[pos] = make_float2(
          (lb != -1.0f) ? (x1 - x0 + 1.0f) * (y1 - y0 + 1.0f) : 1e30f,
          __uint_as_float((unsigned)g));
      sO2S[g] = (unsigned short)pos;
      mspanX = fmaxf(mspanX, x1p - x0);
      mspanY = fmaxf(mspanY, y1p - y0);
    }
  }
#pragma unroll
  for (int m = 32; m > 0; m >>= 1) {
    mspanX = fmaxf(mspanX, __shfl_xor(mspanX, m, 64));
    mspanY = fmaxf(mspanY, __shfl_xor(mspanY, m, 64));
  }
  {
    int lane = threadIdx.x & 63, wid = threadIdx.x >> 6;
    if (lane == 0) { sWaveMax[wid][0] = mspanX; sWaveMax[wid][1] = mspanY; }
  }
  __syncthreads();
  if (threadIdx.x == 0) {
    sSpanX = fmaxf(fmaxf(sWaveMax[0][0], sWaveMax[1][0]),
                   fmaxf(sWaveMax[2][0], sWaveMax[3][0])) + 1.0f;  // +1 px slack
    sSpanY = fmaxf(fmaxf(sWaveMax[0][1], sWaveMax[1][1]),
                   fmaxf(sWaveMax[2][1], sWaveMax[3][1])) + 1.0f;
  }
  __syncthreads();
  const float spanX = sSpanX, spanY = sSpanY;

  float t_cls = 0.f, t_bbox = 0.f, t_iou = 0.f, t_num = 0.f;
  float t_npos = 0.f, t_nfg = 0.f, t_ncnt = 0.f;

  const float BBOX_CLIP = 4.1351666f;  // log(1000/16)

  // ---------------- phase 1: anchor-vs-gt top-2, 2D-banded window ----------
  // Superset proof: any GT with x- AND y-overlap has gx0 in [ax0-spanX, ax1p],
  // gy0 in [ay0-spanY, ay1p] -> its (ybin,xbin) lies in the iterated rectangle
  // (monotone clamped bins, same formula at build and query).
  uint32_t an1 = 0xFFFFFFFFu, an2 = 0xFFFFFFFFu;
  {
    int xb0 = xbin(ax0 - spanX);
    int xb1 = xbin(ax1p);
    int yb0 = ybin(ay0 - spanY);
    int yb1 = ybin(ay1p);
    for (int yb = yb0; yb <= yb1; ++yb) {
      int lo = sStart[(yb << 5) + xb0];
      int hi = sStart[(yb << 5) + xb1 + 1];
#pragma unroll 2
      for (int s = lo + seg; s < hi; s += 2) {
        float4 gb = sBox[s];
        float2 mt = sMeta[s];
        uint32_t pk = packKey(ax0, ay0, ax1p, ay1p, areaa, gb, mt.x,
                              __float_as_uint(mt.y));
        uint32_t h = max(pk, an1);
        an1 = min(an1, pk);
        an2 = min(an2, h);
      }
    }
  }

  // merge the duo's 2 lanes
  {
    uint32_t o1 = (uint32_t)__shfl_xor((int)an1, 1, 64);
    uint32_t o2 = (uint32_t)__shfl_xor((int)an2, 1, 64);
    uint32_t hi = max(an1, o1);
    an1 = min(an1, o1);
    an2 = min(min(an2, o2), hi);
  }

  bool fg0 = false, fg1 = false, needy = false;

  if (seg == 0 && i < A) {
    // winning ORIGINAL indices -> slots (sentinel 0x1FF -> dummy slot G)
    int og0 = (int)(an1 & 0x1FFu);
    int og1 = (int)(an2 & 0x1FFu);
    int s0 = sO2S[og0];
    int s1 = sO2S[og1];

    // exact recompute of winning values (reference op order, explicit validity)
    float4 g0 = sBox[s0]; float a0 = sMeta[s0].x; bool val0 = a0 < 1e29f;
    float v0 = val0 ? iouExact(ax0, ay0, ax1, ay1, areaa, g0, a0) : -1.0f;
    float4 g1 = sBox[s1]; float a1 = sMeta[s1].x; bool val1 = a1 < 1e29f;
    float v1 = val1 ? iouExact(ax0, ay0, ax1, ay1, areaa, g1, a1) : -1.0f;

    // labels: >=0.5 -> 1, <0.4 -> 0, else -1
    float la  = (v0 >= 0.5f) ? 1.0f : ((v0 < 0.4f) ? 0.0f : -1.0f);
    float lbv = (v1 >= 0.5f) ? 1.0f : ((v1 < 0.4f) ? 0.0f : -1.0f);
    float lab0 = la;
    float lab1 = lbv - (((la == 0.0f) && (lbv != 0.0f)) ? 1.0f : 0.0f);

    // ---- focal classification loss ----
    {
      float pv = pcv0;
      if (lab0 != -1.0f) {
        float l = (lab0 == 1.0f)
                      ? 0.25f * (1.0f - pv) * (1.0f - pv) * logf(pv)
                      : 0.75f * pv * pv * logf(1.0f - pv);
        t_cls -= l;
      }
      if (lab0 > 0.f) t_npos += 1.f;
      float qv = pcv1;
      if (lab1 != -1.0f) {
        float l = (lab1 == 1.0f)
                      ? 0.25f * (1.0f - qv) * (1.0f - qv) * logf(qv)
                      : 0.75f * qv * qv * logf(1.0f - qv);
        t_cls -= l;
      }
      if (lab1 > 0.f) t_npos += 1.f;
    }

    fg0 = (lab0 != 0.0f) && (lab0 != -1.0f);
    fg1 = (lab1 != 0.0f) && (lab1 != -1.0f);

    // fast reciprocals for the bbox-target divides (rel err ~1e-7, harmless)
    float raw = __builtin_amdgcn_rcpf(aw), rah = __builtin_amdgcn_rcpf(ah);

    // ---- bbox smooth-L1 vs bbox_transform(anchor, matched gt) ----
    if (fg0) {
      float mx1 = g0.z - 1.0f, my1 = g0.w - 1.0f;
      float gw = mx1 - g0.x + 1.0f, gh = my1 - g0.y + 1.0f;
      float gcx = g0.x + 0.5f * gw, gcy = g0.y + 0.5f * gh;
      float t0 = (gcx - acx) * raw, t1v = (gcy - acy) * rah;
      float t2 = logf(gw * raw), t3 = logf(gh * rah);
      t_bbox += huber9(d0 - t0) + huber9(d1 - t1v) + huber9(d2 - t2) + huber9(d3 - t3);
      t_nfg += 1.f;
    }
    if (fg1) {
      float mx1 = g1.z - 1.0f, my1 = g1.w - 1.0f;
      float gw = mx1 - g1.x + 1.0f, gh = my1 - g1.y + 1.0f;
      float gcx = g1.x + 0.5f * gw, gcy = g1.y + 0.5f * gh;
      float t0 = (gcx - acx) * raw, t1v = (gcy - acy) * rah;
      float t2 = logf(gw * raw), t3 = logf(gh * rah);
      t_bbox += huber9(d4 - t0) + huber9(d5 - t1v) + huber9(d6 - t2) + huber9(d7 - t3);
      t_nfg += 1.f;
    }

    // ---- num softmax loss ----
    {
      int nl = ((lab0 > 0.f) ? 1 : 0) + ((lab1 > 0.f) ? 1 : 0) - 1;
      if (nl != -1) {
        float m = fmaxf(sn0, sn1);
        float lse = m + logf(expf(sn0 - m) + expf(sn1 - m));
        float picked = ((nl == 0) ? sn0 : sn1) - lse;
        t_num -= picked;
        t_ncnt += 1.f;
      }
    }

    // ---- enqueue for phase 2 (decoded-box argmaxes) only if fg ----
    needy = fg0 || fg1;
    if (needy) {
      // decode predicted boxes (identical expressions to the original)
      float p0cx = acx + d0 * aw, p0cy = acy + d1 * ah;
      float p0w = aw * expf(fminf(d2, BBOX_CLIP));
      float p0h = ah * expf(fminf(d3, BBOX_CLIP));
      float b0x0 = p0cx - 0.5f * p0w, b0y0 = p0cy - 0.5f * p0h;
      float b0x1 = p0cx + 0.5f * p0w, b0y1 = p0cy + 0.5f * p0h;
      float area0 = (b0x1 - b0x0 + 1.0f) * (b0y1 - b0y0 + 1.0f);

      float p1cx = acx + d4 * aw, p1cy = acy + d5 * ah;
      float p1w = aw * expf(fminf(d6, BBOX_CLIP));
      float p1h = ah * expf(fminf(d7, BBOX_CLIP));
      float b1x0 = p1cx - 0.5f * p1w, b1y0 = p1cy - 0.5f * p1h;
      float b1x1 = p1cx + 0.5f * p1w, b1y1 = p1cy + 0.5f * p1h;
      float area1 = (b1x1 - b1x0 + 1.0f) * (b1y1 - b1y0 + 1.0f);

      int slot = atomicAdd(&sNum, 1);
      sList[slot] = (unsigned char)duo;
      float* st = sStash[slot];
      st[0] = b0x0; st[1] = b0y0; st[2] = b0x1; st[3] = b0y1; st[4] = area0;
      st[5] = b1x0; st[6] = b1y0; st[7] = b1x1; st[8] = b1y1; st[9] = area1;
    }
  }
  __syncthreads();

  // -------- phase 2: compacted decoded-box argmaxes (2D-banded windows) ------
  {
    int num = sNum;
    for (int sb = 0; sb < num; sb += 64) {
      int slot = sb + (threadIdx.x >> 2);
      int wseg = threadIdx.x & 3;
      if (slot < num) {   // uniform across each quad -> shfl butterfly safe
        const float* st = sStash[slot];
        float c0x0 = st[0], c0y0 = st[1], c0x1 = st[2], c0y1 = st[3], car0 = st[4];
        float c1x0 = st[5], c1y0 = st[6], c1x1 = st[7], c1y1 = st[8], car1 = st[9];
        float c0x1p = c0x1 + 1.0f, c0y1p = c0y1 + 1.0f;
        float c1x1p = c1x1 + 1.0f, c1y1p = c1y1 + 1.0f;

        uint32_t am = 0xFFFFFFFFu;                     // box 0 best
        uint32_t bk1 = 0xFFFFFFFFu, bk2 = 0xFFFFFFFFu; // box 1 best/2nd

        // union 2D window of both decoded boxes (clamped bins handle wild
        // extents; extra GTs are zero-overlap -> invariant)
        int xb0 = xbin(fminf(c0x0, c1x0) - spanX);
        int xb1 = xbin(fmaxf(c0x1p, c1x1p));
        int yb0 = ybin(fminf(c0y0, c1y0) - spanY);
        int yb1 = ybin(fmaxf(c0y1p, c1y1p));
        for (int yb = yb0; yb <= yb1; ++yb) {
          int lo = sStart[(yb << 5) + xb0];
          int hi = sStart[(yb << 5) + xb1 + 1];
#pragma unroll 2
          for (int s = lo + wseg; s < hi; s += 4) {
            float4 gb = sBox[s];
            float2 mt = sMeta[s];
            uint32_t og = __float_as_uint(mt.y);
            am = min(am, packKey(c0x0, c0y0, c0x1p, c0y1p, car0, gb, mt.x, og));
            uint32_t pk = packKey(c1x0, c1y0, c1x1p, c1y1p, car1, gb, mt.x, og);
            uint32_t hib = max(pk, bk1);
            bk1 = min(bk1, pk);
            bk2 = min(bk2, hib);
          }
        }

#pragma unroll
        for (int m = 1; m <= 2; m <<= 1) {
          am = min(am, (uint32_t)__shfl_xor((int)am, m, 64));
          uint32_t q1 = (uint32_t)__shfl_xor((int)bk1, m, 64);
          uint32_t q2 = (uint32_t)__shfl_xor((int)bk2, m, 64);
          uint32_t hib = max(bk1, q1);
          bk1 = min(bk1, q1);
          bk2 = min(min(bk2, q2), hib);
        }

        if (wseg == 0) {
          int ai  = (int)(am  & 0x1FFu);  // ORIGINAL indices (reference semantics)
          int bi  = (int)(bk1 & 0x1FFu);
          int bi2 = (int)(bk2 & 0x1FFu);
          int sa = sO2S[ai];
          float4 ga4 = sBox[sa]; float aav = sMeta[sa].x;
          float aval = (aav < 1e29f) ? iouExact(c0x0, c0y0, c0x1, c0y1, car0, ga4, aav) : 0.0f;
          int bIdx = (ai == bi) ? bi2 : bi;  // b with b[ai] zeroed, then argmax
          int sb2 = sO2S[bIdx];
          float4 gb4 = sBox[sb2]; float abv = sMeta[sb2].x;
          float bval = (abv < 1e29f) ? iouExact(c1x0, c1y0, c1x1, c1y1, car1, gb4, abv) : 0.0f;
          sRes[sList[slot]] = make_float2(aval, bval);
        }
      }
    }
  }
  __syncthreads();

  // ---- IoU L1 loss (owner lane reads phase-2 result) ----
  if (needy) {   // implies seg==0 && i<A
    float2 r = sRes[duo];
    if (fg0) t_iou += fabsf(riv0 - r.x);
    if (fg1) t_iou += fabsf(riv1 - fmaxf(r.y, 0.0f));
  }

  // block reduction: wave shuffle -> LDS -> one private record per block.
  // NO global atomics, NO device fences (r10: all-thread __threadfence caused
  // an L2-writeback storm, 55 -> 172 us; finalize reads partials across the
  // kernel boundary instead -- the proven-safe r2-r9 pattern).
  float vals[7] = {t_cls, t_bbox, t_iou, t_num, t_npos, t_nfg, t_ncnt};
  int lane = threadIdx.x & 63;
  int wid = threadIdx.x >> 6;
#pragma unroll
  for (int k = 0; k < 7; ++k) {
    float s = waveSum(vals[k]);
    if (lane == 0) sRed[wid][k] = s;
  }
  __syncthreads();
  if (threadIdx.x < 7) {
    double s = (double)sRed[0][threadIdx.x] + (double)sRed[1][threadIdx.x] +
               (double)sRed[2][threadIdx.x] + (double)sRed[3][threadIdx.x];
    size_t bid = (size_t)blockIdx.y * gridDim.x + blockIdx.x;
    partial[bid * 8 + threadIdx.x] = s;    // 64-B record, no contention
  }
}

// Second dispatch on the same stream: kernel-boundary ordering makes the
// partial records visible. Sums nB x 7 doubles (~60 KB, L2-resident).
__global__ __launch_bounds__(1024) void retina_finalize(
    const double* __restrict__ partial, int nB, float* __restrict__ out) {
  __shared__ double sRed[16][7];
  double loc[7] = {0.0, 0.0, 0.0, 0.0, 0.0, 0.0, 0.0};
  for (int b = threadIdx.x; b < nB; b += 1024) {
    const double* r = partial + (size_t)b * 8;
#pragma unroll
    for (int k = 0; k < 7; ++k) loc[k] += r[k];
  }
  int lane = threadIdx.x & 63;
  int wid = threadIdx.x >> 6;
#pragma unroll
  for (int k = 0; k < 7; ++k) {
    double v = loc[k];
#pragma unroll
    for (int o = 32; o > 0; o >>= 1) v += __shfl_down(v, o, 64);
    if (lane == 0) sRed[wid][k] = v;
  }
  __syncthreads();
  if (threadIdx.x == 0) {
    double t[7];
#pragma unroll
    for (int k = 0; k < 7; ++k) {
      double s = 0.0;
      for (int w = 0; w < 16; ++w) s += sRed[w][k];
      t[k] = s;
    }
    double dpos = t[4] > 1.0 ? t[4] : 1.0;
    double dfg  = t[5] > 1.0 ? t[5] : 1.0;
    double dcnt = t[6] > 1.0 ? t[6] : 1.0;
    out[0] = (float)(t[0] / dpos);
    out[1] = (float)(2.0 * t[1] / dfg);
    out[2] = (float)(2.0 * t[2] / dfg);
    out[3] = (float)(t[3] / dcnt);
  }
}

extern "C" void kernel_launch(void* const* d_in, const int* in_sizes, int n_in,
                              void* d_out, int out_size, void* d_ws, size_t ws_size,
                              hipStream_t stream) {
  const float* pred_cls = (const float*)d_in[0];
  const float* rpn_num  = (const float*)d_in[1];
  const float* pred_reg = (const float*)d_in[2];
  const float* anchors  = (const float*)d_in[3];
  const float* rpn_iou  = (const float*)d_in[4];
  const float* boxes    = (const float*)d_in[5];
  // d_in[6] = im_info: unused by the reference math

  int A = in_sizes[3] / 4;
  int n = in_sizes[0] / (2 * A);
  int G = in_sizes[5] / (5 * n);

  double* partial = (double*)d_ws;  // (nB, 8) doubles = 64 B per block

  int nBx = (A + 127) / 128;  // 128 anchors per block (SPLIT=2)
  int nB = nBx * n;
  dim3 grid(nBx, n, 1);
  // TWO dispatches total (wall model: ~60 us fixed + kernels + ~6 us/dispatch)
  retina_main<<<grid, dim3(256, 1, 1), 0, stream>>>(
      pred_cls, rpn_num, pred_reg, anchors, rpn_iou, boxes, A, G, partial);
  retina_finalize<<<dim3(1, 1, 1), dim3(1024, 1, 1), 0, stream>>>(
      partial, nB, (float*)d_out);
}

// Round 12
// 119.841 us; speedup vs baseline: 1.9215x; 1.0713x over previous
//
#include <hip/hip_runtime.h>
#include <math.h>

#define G_MAX 384    // slot capacity (G=300 + dummies); requires G <= 383
#define O2S_MAX 512  // og sentinel 0x1FF must stay in-bounds

// 2D GT bins: 16 y-bands x 32 x-bins over [0, 900] (clamped, monotone)
#define XB 32
#define YB 16
#define NBINS 512
#define SCLX (32.0f / 900.0f)
#define SCLY (16.0f / 900.0f)

__device__ __forceinline__ int xbin(float v) {
  int b = (int)(v * SCLX);            // trunc: monotone non-decreasing
  return min(max(b, 0), XB - 1);
}
__device__ __forceinline__ int ybin(float v) {
  int b = (int)(v * SCLY);
  return min(max(b, 0), YB - 1);
}

__device__ __forceinline__ float waveSum(float v) {
#pragma unroll
  for (int o = 32; o > 0; o >>= 1) v += __shfl_down(v, o, 64);
  return v;
}

// smooth-L1 with sigma=3 (s2=9)
__device__ __forceinline__ float huber9(float x) {
  float ax = fabsf(x);
  return (ax < (1.0f / 9.0f)) ? 4.5f * x * x : ax - (0.5f / 9.0f);
}

// Exact IoU in the reference's op order. g = (x0, y0, x1+1, y1+1)
__device__ __forceinline__ float iouExact(float bx0, float by0, float bx1, float by1,
                                          float areab, float4 g, float areag) {
  float gx1 = g.z - 1.0f, gy1 = g.w - 1.0f;  // exact inverse of staged +1 (coords < 2^24)
  float iw = fminf(bx1, gx1) - fmaxf(bx0, g.x) + 1.0f;
  float ih = fminf(by1, gy1) - fmaxf(by0, g.y) + 1.0f;
  float inter = fmaxf(iw, 0.f) * fmaxf(ih, 0.f);
  float uni = areab + areag - inter;
  return inter / fmaxf(uni, 1.0f);
}

// Inverse comparison key: key = (areaB+areaG)*rcp(inter); argmax iou == argmin
// key (uint compare on positive floats). ONE-CLAMP trick: inter = max(iw,0)*ih.
//   ih >= 0: identical to the two-clamp value (positive-overlap keys exact).
//   ih <  0: key negative/-inf -> uint >= 0x80000000 -> loses under min-tracking.
//   iw <= 0, ih > 0: inter = +0 -> key = +inf -> loses to all finite positives.
// Zero-overlap/invalid internal order is output-invariant (winners recomputed
// exactly with validity masks -> label 0 / fg=false / value 0). 2D-band
// pruning only removes members of this class (pruned GT fails x- or
// y-overlap by the monotone-bin argument) -> output unchanged.
// Low 9 bits carry ORIGINAL g: min-ties resolve to smallest g (jax stable).
__device__ __forceinline__ uint32_t packKey(float x0, float y0, float x1p, float y1p,
                                            float area, float4 gb, float ga,
                                            uint32_t g) {
  float iw = fminf(x1p, gb.z) - fmaxf(x0, gb.x);
  float ih = fminf(y1p, gb.w) - fmaxf(y0, gb.y);
  float inter = fmaxf(iw, 0.f) * ih;
  float key = (area + ga) * __builtin_amdgcn_rcpf(inter);
  return (__float_as_uint(key) & 0xFFFFFE00u) | g;
}

__global__ __launch_bounds__(256) void retina_main(
    const float* __restrict__ pred_cls,   // (n, A, 2)
    const float* __restrict__ rpn_num,    // (n, A, 2)
    const float* __restrict__ pred_reg,   // (n, A, 8)
    const float* __restrict__ anchors,    // (A, 4)
    const float* __restrict__ rpn_iou,    // (n, A, 2)
    const float* __restrict__ boxes,      // (n, G, 5)
    int A, int G,
    double* __restrict__ partial)         // (nB, 8) doubles, private per block
{
  __shared__ float4 sBox[G_MAX];          // (yband,xbin)-ordered: x0,y0,x1+1,y1+1
  __shared__ float2 sMeta[G_MAX];         // (area | 1e30 invalid, orig-g bits)
  __shared__ unsigned short sO2S[O2S_MAX];// orig g (incl. 0x1FF sentinel) -> slot
  __shared__ int sCnt[NBINS];             // hist, then scatter cursors
  __shared__ int sStart[NBINS + 1];       // exclusive prefix (window table)
  __shared__ int sWsum[4];
  __shared__ float sWaveMax[4][2];
  __shared__ float sSpanX, sSpanY;
  __shared__ float sRed[4][7];
  __shared__ float sStash[256][10];       // decoded boxes of needy anchors
  __shared__ float2 sRes[256];            // aval/bval results (by owner lane)
  __shared__ unsigned char sList[256];    // slot -> owner lane
  __shared__ int sNum;

  // SPLIT=1: one lane owns one anchor end-to-end. No duo merge; epilogue and
  // enqueue run FULL-WIDTH (r11's seg==0 masking issued the entire epilogue
  // at half lane-utilization -- 2x issue waste on the invariant core).
  const int img = blockIdx.y;
  const int own = threadIdx.x;
  const int i   = blockIdx.x * 256 + own;
  const int ic  = (i < A) ? i : (A - 1);
  const float* gtb = boxes + (size_t)img * G * 5;

  // ---- hoisted per-anchor loads (all-lane, coalesced): latency hides under prep
  float4 a4 = *(const float4*)(anchors + (size_t)ic * 4);
  float ax0 = a4.x, ay0 = a4.y, ax1 = a4.z, ay1 = a4.w;
  float aw = ax1 - ax0 + 1.0f, ah = ay1 - ay0 + 1.0f;
  float areaa = aw * ah;
  float acx = ax0 + 0.5f * aw, acy = ay0 + 0.5f * ah;
  float ax1p = ax1 + 1.0f, ay1p = ay1 + 1.0f;

  const float* dp = pred_reg + ((size_t)img * A + ic) * 8;
  float d0 = dp[0], d1 = dp[1], d2 = dp[2], d3 = dp[3];
  float d4 = dp[4], d5 = dp[5], d6 = dp[6], d7 = dp[7];
  const float* pc = pred_cls + ((size_t)img * A + ic) * 2;
  float pcv0 = pc[0], pcv1 = pc[1];
  const float* ri = rpn_iou + ((size_t)img * A + ic) * 2;
  float riv0 = ri[0], riv1 = ri[1];
  const float* sp = rpn_num + ((size_t)img * A + ic) * 2;
  float sn0 = sp[0], sn1 = sp[1];

  // ---- in-block GT prep: counting sort by (yband, xbin) ----
  if (threadIdx.x == 0) sNum = 0;
  for (int b = threadIdx.x; b < NBINS; b += 256) sCnt[b] = 0;
  // dummy slots [G, G_MAX) + sentinel map entries [G, O2S_MAX) -> dummy slot G
  for (int s = G + threadIdx.x; s < G_MAX; s += 256) {
    sBox[s] = make_float4(0.f, 0.f, 1.f, 1.f);
    sMeta[s] = make_float2(1e30f, __uint_as_float((unsigned)s));
  }
  for (int s = G + threadIdx.x; s < O2S_MAX; s += 256)
    sO2S[s] = (unsigned short)G;
  __syncthreads();

  // one global pass: cache rows in registers (G<=512 -> <=2 rows per thread)
  float rx0[2], ry0[2], rx1[2], ry1[2], rlb[2];
  int ng = 0;
  for (int g = threadIdx.x; g < G; g += 256, ++ng) {
    rx0[ng] = gtb[g * 5 + 0]; ry0[ng] = gtb[g * 5 + 1];
    rx1[ng] = gtb[g * 5 + 2]; ry1[ng] = gtb[g * 5 + 3];
    rlb[ng] = gtb[g * 5 + 4];
    atomicAdd(&sCnt[(ybin(ry0[ng]) << 5) | xbin(rx0[ng])], 1);
  }
  __syncthreads();

  // wave-scan exclusive prefix over 512 bins (2 bins/thread)
  {
    int t = threadIdx.x;
    int b0 = sCnt[t * 2 + 0], b1 = sCnt[t * 2 + 1];
    int tsum = b0 + b1;
    int lane = t & 63, wid = t >> 6;
    int incl = tsum;
#pragma unroll
    for (int o = 1; o < 64; o <<= 1) {
      int u = __shfl_up(incl, o, 64);
      if (lane >= o) incl += u;
    }
    if (lane == 63) sWsum[wid] = incl;
    __syncthreads();
    int woff = 0;
    for (int w = 0; w < wid; ++w) woff += sWsum[w];   // uniform per wave
    int excl = woff + incl - tsum;
    sStart[t * 2 + 0] = excl;
    sStart[t * 2 + 1] = excl + b0;
    if (t == 255) sStart[NBINS] = excl + tsum;        // == G
    sCnt[t * 2 + 0] = excl;
    sCnt[t * 2 + 1] = excl + b0;
  }
  __syncthreads();

  // scatter (within-bin order arbitrary: harmless, keys carry orig g)
  float mspanX = 0.f, mspanY = 0.f;
  {
    int g = threadIdx.x;
    for (int k = 0; k < ng; ++k, g += 256) {
      float x0 = rx0[k], y0 = ry0[k], x1 = rx1[k], y1 = ry1[k], lb = rlb[k];
      int pos = atomicAdd(&sCnt[(ybin(y0) << 5) | xbin(x0)], 1);
      float x1p = x1 + 1.0f, y1p = y1 + 1.0f;
      sBox[pos] = make_float4(x0, y0, x1p, y1p);
      sMeta[pos] = make_float2(
          (lb != -1.0f) ? (x1 - x0 + 1.0f) * (y1 - y0 + 1.0f) : 1e30f,
          __uint_as_float((unsigned)g));
      sO2S[g] = (unsigned short)pos;
      mspanX = fmaxf(mspanX, x1p - x0);
      mspanY = fmaxf(mspanY, y1p - y0);
    }
  }
#pragma unroll
  for (int m = 32; m > 0; m >>= 1) {
    mspanX = fmaxf(mspanX, __shfl_xor(mspanX, m, 64));
    mspanY = fmaxf(mspanY, __shfl_xor(mspanY, m, 64));
  }
  {
    int lane = threadIdx.x & 63, wid = threadIdx.x >> 6;
    if (lane == 0) { sWaveMax[wid][0] = mspanX; sWaveMax[wid][1] = mspanY; }
  }
  __syncthreads();
  if (threadIdx.x == 0) {
    sSpanX = fmaxf(fmaxf(sWaveMax[0][0], sWaveMax[1][0]),
                   fmaxf(sWaveMax[2][0], sWaveMax[3][0])) + 1.0f;  // +1 px slack
    sSpanY = fmaxf(fmaxf(sWaveMax[0][1], sWaveMax[1][1]),
                   fmaxf(sWaveMax[2][1], sWaveMax[3][1])) + 1.0f;
  }
  __syncthreads();
  const float spanX = sSpanX, spanY = sSpanY;

  float t_cls = 0.f, t_bbox = 0.f, t_iou = 0.f, t_num = 0.f;
  float t_npos = 0.f, t_nfg = 0.f, t_ncnt = 0.f;

  const float BBOX_CLIP = 4.1351666f;  // log(1000/16)

  // ---------------- phase 1: anchor-vs-gt top-2, 2D-banded window ----------
  // Superset proof: any GT with x- AND y-overlap has gx0 in [ax0-spanX, ax1p],
  // gy0 in [ay0-spanY, ay1p] -> its (ybin,xbin) lies in the iterated rectangle
  // (monotone clamped bins, same formula at build and query).
  uint32_t an1 = 0xFFFFFFFFu, an2 = 0xFFFFFFFFu;
  {
    int xb0 = xbin(ax0 - spanX);
    int xb1 = xbin(ax1p);
    int yb0 = ybin(ay0 - spanY);
    int yb1 = ybin(ay1p);
    for (int yb = yb0; yb <= yb1; ++yb) {
      int lo = sStart[(yb << 5) + xb0];
      int hi = sStart[(yb << 5) + xb1 + 1];
#pragma unroll 2
      for (int s = lo; s < hi; ++s) {
        float4 gb = sBox[s];
        float2 mt = sMeta[s];
        uint32_t pk = packKey(ax0, ay0, ax1p, ay1p, areaa, gb, mt.x,
                              __float_as_uint(mt.y));
        uint32_t h = max(pk, an1);
        an1 = min(an1, pk);
        an2 = min(an2, h);
      }
    }
  }

  bool fg0 = false, fg1 = false, needy = false;

  if (i < A) {
    // winning ORIGINAL indices -> slots (sentinel 0x1FF -> dummy slot G)
    int og0 = (int)(an1 & 0x1FFu);
    int og1 = (int)(an2 & 0x1FFu);
    int s0 = sO2S[og0];
    int s1 = sO2S[og1];

    // exact recompute of winning values (reference op order, explicit validity)
    float4 g0 = sBox[s0]; float a0 = sMeta[s0].x; bool val0 = a0 < 1e29f;
    float v0 = val0 ? iouExact(ax0, ay0, ax1, ay1, areaa, g0, a0) : -1.0f;
    float4 g1 = sBox[s1]; float a1 = sMeta[s1].x; bool val1 = a1 < 1e29f;
    float v1 = val1 ? iouExact(ax0, ay0, ax1, ay1, areaa, g1, a1) : -1.0f;

    // labels: >=0.5 -> 1, <0.4 -> 0, else -1
    float la  = (v0 >= 0.5f) ? 1.0f : ((v0 < 0.4f) ? 0.0f : -1.0f);
    float lbv = (v1 >= 0.5f) ? 1.0f : ((v1 < 0.4f) ? 0.0f : -1.0f);
    float lab0 = la;
    float lab1 = lbv - (((la == 0.0f) && (lbv != 0.0f)) ? 1.0f : 0.0f);

    // ---- focal classification loss ----
    {
      float pv = pcv0;
      if (lab0 != -1.0f) {
        float l = (lab0 == 1.0f)
                      ? 0.25f * (1.0f - pv) * (1.0f - pv) * logf(pv)
                      : 0.75f * pv * pv * logf(1.0f - pv);
        t_cls -= l;
      }
      if (lab0 > 0.f) t_npos += 1.f;
      float qv = pcv1;
      if (lab1 != -1.0f) {
        float l = (lab1 == 1.0f)
                      ? 0.25f * (1.0f - qv) * (1.0f - qv) * logf(qv)
                      : 0.75f * qv * qv * logf(1.0f - qv);
        t_cls -= l;
      }
      if (lab1 > 0.f) t_npos += 1.f;
    }

    fg0 = (lab0 != 0.0f) && (lab0 != -1.0f);
    fg1 = (lab1 != 0.0f) && (lab1 != -1.0f);

    // fast reciprocals for the bbox-target divides (rel err ~1e-7, harmless)
    float raw = __builtin_amdgcn_rcpf(aw), rah = __builtin_amdgcn_rcpf(ah);

    // ---- bbox smooth-L1 vs bbox_transform(anchor, matched gt) ----
    if (fg0) {
      float mx1 = g0.z - 1.0f, my1 = g0.w - 1.0f;
      float gw = mx1 - g0.x + 1.0f, gh = my1 - g0.y + 1.0f;
      float gcx = g0.x + 0.5f * gw, gcy = g0.y + 0.5f * gh;
      float t0 = (gcx - acx) * raw, t1v = (gcy - acy) * rah;
      float t2 = logf(gw * raw), t3 = logf(gh * rah);
      t_bbox += huber9(d0 - t0) + huber9(d1 - t1v) + huber9(d2 - t2) + huber9(d3 - t3);
      t_nfg += 1.f;
    }
    if (fg1) {
      float mx1 = g1.z - 1.0f, my1 = g1.w - 1.0f;
      float gw = mx1 - g1.x + 1.0f, gh = my1 - g1.y + 1.0f;
      float gcx = g1.x + 0.5f * gw, gcy = g1.y + 0.5f * gh;
      float t0 = (gcx - acx) * raw, t1v = (gcy - acy) * rah;
      float t2 = logf(gw * raw), t3 = logf(gh * rah);
      t_bbox += huber9(d4 - t0) + huber9(d5 - t1v) + huber9(d6 - t2) + huber9(d7 - t3);
      t_nfg += 1.f;
    }

    // ---- num softmax loss ----
    {
      int nl = ((lab0 > 0.f) ? 1 : 0) + ((lab1 > 0.f) ? 1 : 0) - 1;
      if (nl != -1) {
        float m = fmaxf(sn0, sn1);
        float lse = m + logf(expf(sn0 - m) + expf(sn1 - m));
        float picked = ((nl == 0) ? sn0 : sn1) - lse;
        t_num -= picked;
        t_ncnt += 1.f;
      }
    }

    // ---- enqueue for phase 2 (decoded-box argmaxes) only if fg ----
    needy = fg0 || fg1;
    if (needy) {
      // decode predicted boxes (identical expressions to the original)
      float p0cx = acx + d0 * aw, p0cy = acy + d1 * ah;
      float p0w = aw * expf(fminf(d2, BBOX_CLIP));
      float p0h = ah * expf(fminf(d3, BBOX_CLIP));
      float b0x0 = p0cx - 0.5f * p0w, b0y0 = p0cy - 0.5f * p0h;
      float b0x1 = p0cx + 0.5f * p0w, b0y1 = p0cy + 0.5f * p0h;
      float area0 = (b0x1 - b0x0 + 1.0f) * (b0y1 - b0y0 + 1.0f);

      float p1cx = acx + d4 * aw, p1cy = acy + d5 * ah;
      float p1w = aw * expf(fminf(d6, BBOX_CLIP));
      float p1h = ah * expf(fminf(d7, BBOX_CLIP));
      float b1x0 = p1cx - 0.5f * p1w, b1y0 = p1cy - 0.5f * p1h;
      float b1x1 = p1cx + 0.5f * p1w, b1y1 = p1cy + 0.5f * p1h;
      float area1 = (b1x1 - b1x0 + 1.0f) * (b1y1 - b1y0 + 1.0f);

      int slot = atomicAdd(&sNum, 1);
      sList[slot] = (unsigned char)own;
      float* st = sStash[slot];
      st[0] = b0x0; st[1] = b0y0; st[2] = b0x1; st[3] = b0y1; st[4] = area0;
      st[5] = b1x0; st[6] = b1y0; st[7] = b1x1; st[8] = b1y1; st[9] = area1;
    }
  }
  __syncthreads();

  // -------- phase 2: compacted decoded-box argmaxes (2D-banded windows) ------
  {
    int num = sNum;
    for (int sb = 0; sb < num; sb += 64) {
      int slot = sb + (threadIdx.x >> 2);
      int wseg = threadIdx.x & 3;
      if (slot < num) {   // uniform across each quad -> shfl butterfly safe
        const float* st = sStash[slot];
        float c0x0 = st[0], c0y0 = st[1], c0x1 = st[2], c0y1 = st[3], car0 = st[4];
        float c1x0 = st[5], c1y0 = st[6], c1x1 = st[7], c1y1 = st[8], car1 = st[9];
        float c0x1p = c0x1 + 1.0f, c0y1p = c0y1 + 1.0f;
        float c1x1p = c1x1 + 1.0f, c1y1p = c1y1 + 1.0f;

        uint32_t am = 0xFFFFFFFFu;                     // box 0 best
        uint32_t bk1 = 0xFFFFFFFFu, bk2 = 0xFFFFFFFFu; // box 1 best/2nd

        // union 2D window of both decoded boxes (clamped bins handle wild
        // extents; extra GTs are zero-overlap -> invariant)
        int xb0 = xbin(fminf(c0x0, c1x0) - spanX);
        int xb1 = xbin(fmaxf(c0x1p, c1x1p));
        int yb0 = ybin(fminf(c0y0, c1y0) - spanY);
        int yb1 = ybin(fmaxf(c0y1p, c1y1p));
        for (int yb = yb0; yb <= yb1; ++yb) {
          int lo = sStart[(yb << 5) + xb0];
          int hi = sStart[(yb << 5) + xb1 + 1];
#pragma unroll 2
          for (int s = lo + wseg; s < hi; s += 4) {
            float4 gb = sBox[s];
            float2 mt = sMeta[s];
            uint32_t og = __float_as_uint(mt.y);
            am = min(am, packKey(c0x0, c0y0, c0x1p, c0y1p, car0, gb, mt.x, og));
            uint32_t pk = packKey(c1x0, c1y0, c1x1p, c1y1p, car1, gb, mt.x, og);
            uint32_t hib = max(pk, bk1);
            bk1 = min(bk1, pk);
            bk2 = min(bk2, hib);
          }
        }

#pragma unroll
        for (int m = 1; m <= 2; m <<= 1) {
          am = min(am, (uint32_t)__shfl_xor((int)am, m, 64));
          uint32_t q1 = (uint32_t)__shfl_xor((int)bk1, m, 64);
          uint32_t q2 = (uint32_t)__shfl_xor((int)bk2, m, 64);
          uint32_t hib = max(bk1, q1);
          bk1 = min(bk1, q1);
          bk2 = min(min(bk2, q2), hib);
        }

        if (wseg == 0) {
          int ai  = (int)(am  & 0x1FFu);  // ORIGINAL indices (reference semantics)
          int bi  = (int)(bk1 & 0x1FFu);
          int bi2 = (int)(bk2 & 0x1FFu);
          int sa = sO2S[ai];
          float4 ga4 = sBox[sa]; float aav = sMeta[sa].x;
          float aval = (aav < 1e29f) ? iouExact(c0x0, c0y0, c0x1, c0y1, car0, ga4, aav) : 0.0f;
          int bIdx = (ai == bi) ? bi2 : bi;  // b with b[ai] zeroed, then argmax
          int sb2 = sO2S[bIdx];
          float4 gb4 = sBox[sb2]; float abv = sMeta[sb2].x;
          float bval = (abv < 1e29f) ? iouExact(c1x0, c1y0, c1x1, c1y1, car1, gb4, abv) : 0.0f;
          sRes[sList[slot]] = make_float2(aval, bval);
        }
      }
    }
  }
  __syncthreads();

  // ---- IoU L1 loss (owner lane reads phase-2 result) ----
  if (needy) {   // implies i<A
    float2 r = sRes[own];
    if (fg0) t_iou += fabsf(riv0 - r.x);
    if (fg1) t_iou += fabsf(riv1 - fmaxf(r.y, 0.0f));
  }

  // block reduction: wave shuffle -> LDS -> one private record per block.
  // NO global atomics, NO device fences (r10: all-thread __threadfence caused
  // an L2-writeback storm, 55 -> 172 us; finalize reads partials across the
  // kernel boundary instead -- the proven-safe r2-r9 pattern).
  float vals[7] = {t_cls, t_bbox, t_iou, t_num, t_npos, t_nfg, t_ncnt};
  int lane = threadIdx.x & 63;
  int wid = threadIdx.x >> 6;
#pragma unroll
  for (int k = 0; k < 7; ++k) {
    float s = waveSum(vals[k]);
    if (lane == 0) sRed[wid][k] = s;
  }
  __syncthreads();
  if (threadIdx.x < 7) {
    double s = (double)sRed[0][threadIdx.x] + (double)sRed[1][threadIdx.x] +
               (double)sRed[2][threadIdx.x] + (double)sRed[3][threadIdx.x];
    size_t bid = (size_t)blockIdx.y * gridDim.x + blockIdx.x;
    partial[bid * 8 + threadIdx.x] = s;    // 64-B record, no contention
  }
}

// Second dispatch on the same stream: kernel-boundary ordering makes the
// partial records visible. Sums nB x 7 doubles (~60 KB, L2-resident).
__global__ __launch_bounds__(1024) void retina_finalize(
    const double* __restrict__ partial, int nB, float* __restrict__ out) {
  __shared__ double sRed[16][7];
  double loc[7] = {0.0, 0.0, 0.0, 0.0, 0.0, 0.0, 0.0};
  for (int b = threadIdx.x; b < nB; b += 1024) {
    const double* r = partial + (size_t)b * 8;
#pragma unroll
    for (int k = 0; k < 7; ++k) loc[k] += r[k];
  }
  int lane = threadIdx.x & 63;
  int wid = threadIdx.x >> 6;
#pragma unroll
  for (int k = 0; k < 7; ++k) {
    double v = loc[k];
#pragma unroll
    for (int o = 32; o > 0; o >>= 1) v += __shfl_down(v, o, 64);
    if (lane == 0) sRed[wid][k] = v;
  }
  __syncthreads();
  if (threadIdx.x == 0) {
    double t[7];
#pragma unroll
    for (int k = 0; k < 7; ++k) {
      double s = 0.0;
      for (int w = 0; w < 16; ++w) s += sRed[w][k];
      t[k] = s;
    }
    double dpos = t[4] > 1.0 ? t[4] : 1.0;
    double dfg  = t[5] > 1.0 ? t[5] : 1.0;
    double dcnt = t[6] > 1.0 ? t[6] : 1.0;
    out[0] = (float)(t[0] / dpos);
    out[1] = (float)(2.0 * t[1] / dfg);
    out[2] = (float)(2.0 * t[2] / dfg);
    out[3] = (float)(t[3] / dcnt);
  }
}

extern "C" void kernel_launch(void* const* d_in, const int* in_sizes, int n_in,
                              void* d_out, int out_size, void* d_ws, size_t ws_size,
                              hipStream_t stream) {
  const float* pred_cls = (const float*)d_in[0];
  const float* rpn_num  = (const float*)d_in[1];
  const float* pred_reg = (const float*)d_in[2];
  const float* anchors  = (const float*)d_in[3];
  const float* rpn_iou  = (const float*)d_in[4];
  const float* boxes    = (const float*)d_in[5];
  // d_in[6] = im_info: unused by the reference math

  int A = in_sizes[3] / 4;
  int n = in_sizes[0] / (2 * A);
  int G = in_sizes[5] / (5 * n);

  double* partial = (double*)d_ws;  // (nB, 8) doubles = 64 B per block

  int nBx = (A + 255) / 256;  // 256 anchors per block (SPLIT=1)
  int nB = nBx * n;
  dim3 grid(nBx, n, 1);
  // TWO dispatches total (wall model: ~60 us fixed + kernels + ~6 us/dispatch)
  retina_main<<<grid, dim3(256, 1, 1), 0, stream>>>(
      pred_cls, rpn_num, pred_reg, anchors, rpn_iou, boxes, A, G, partial);
  retina_finalize<<<dim3(1, 1, 1), dim3(1024, 1, 1), 0, stream>>>(
      partial, nB, (float*)d_out);
}